// Round 2
// baseline (378.639 us; speedup 1.0000x reference)
//
#include <hip/hip_runtime.h>

#define BATCH 64
#define SEQ   128
#define NLAB  32

// ---------------------------------------------------------------------------
// Kernel 1: per-cell label reduction (unchanged from R1 — counters next round
// will show its true cost).
//   pot[b,i,j] = max_l (logits' + 1 - gold_onehot + special_augment)
//   gold[b]   += logits'[b,i,j,label]
// ---------------------------------------------------------------------------
__global__ __launch_bounds__(256) void pot_gold_kernel(
    const float* __restrict__ logits, const int* __restrict__ labels,
    float* __restrict__ pot, float* __restrict__ gold, int* __restrict__ lenbuf)
{
    const int blk = blockIdx.x;
    const int b = blk >> 7;        // / SEQ
    const int i = blk & (SEQ - 1); // % SEQ
    const int tid = threadIdx.x;

    __shared__ int s_len;
    __shared__ float s_red[4];

    int len = SEQ;
    if (i == 0) {
        if (tid == 0) s_len = 0;
        __syncthreads();
        if (tid < SEQ) {
            int lab = labels[(size_t)b * SEQ * SEQ + tid];
            unsigned long long m = __ballot(lab != -100);
            if ((tid & 63) == 0) atomicAdd(&s_len, __popcll(m));
        }
        __syncthreads();
        len = s_len;
        if (tid == 0) lenbuf[b] = len;
    }

    const int s = tid & 7;        // sub-lane within cell group (0..7)
    const int cell = tid >> 3;    // 0..31 cells per iteration
    float gsum = 0.0f;

    const size_t row_base = (size_t)(b * SEQ + i) * SEQ;

    for (int t = 0; t < 4; ++t) {
        const int j = t * 32 + cell;
        const float4 v = reinterpret_cast<const float4*>(
            logits + ((row_base + j) << 5))[s];
        const int lab = labels[row_base + j];
        const int lab_eff = lab < 0 ? 0 : lab;

        const float l0 = __shfl(v.x, 0, 8);   // logits[...,0] of this cell
        float rr[4] = { v.x - l0, v.y - l0, v.z - l0, v.w - l0 };

        // gold contribution: logits'[label]
        const float cand = rr[lab_eff & 3];
        const float goldc = __shfl(cand, lab_eff >> 2, 8);

        // cost-augmented max over labels
        const bool special = (i == 0) && (j == len - 1);
        const int lbase = s << 2;
        float m = -3.0e38f;
        #pragma unroll
        for (int c = 0; c < 4; ++c) {
            const int l = lbase + c;
            float tv = rr[c] + 1.0f - (l == lab_eff ? 1.0f : 0.0f);
            if (special && l == 0) tv -= 1.0e9f;
            m = fmaxf(m, tv);
        }
        #pragma unroll
        for (int d = 4; d > 0; d >>= 1)
            m = fmaxf(m, __shfl_down(m, d, 8));

        if (s == 0) {
            pot[row_base + j] = m;
            gsum += goldc;
        }
    }

    #pragma unroll
    for (int d = 32; d > 0; d >>= 1) gsum += __shfl_down(gsum, d, 64);
    const int wave = tid >> 6;
    if ((tid & 63) == 0) s_red[wave] = gsum;
    __syncthreads();
    if (tid == 0) {
        atomicAdd(&gold[b], s_red[0] + s_red[1] + s_red[2] + s_red[3]);
    }
}

// ---------------------------------------------------------------------------
// Kernel 2 (v2): max-plus CKY, one block per batch element.
// Single-table formulation (Bt[j][m] == A[j-m][m]):
//   A[i][w] = P[i][i+w] + max_{k<w} A[i][k] + A[i+k+1][w-1-k]
// LDS: A[128][130] (66.5 KB, pitch 130 -> both access strides land on
// distinct-ish banks, worst 4-way) + P[128][128] staged pot tile (64 KB)
// so NO global loads on the step critical path. Total 132 KB < 160 KB.
// tpe = floor_pow2(256/entries): one pass covers all entries, >=50% lanes on.
// ---------------------------------------------------------------------------
__global__ __launch_bounds__(256, 1) void cky_kernel(
    const float* __restrict__ pot, const float* __restrict__ gold,
    const int* __restrict__ lenbuf, float* __restrict__ out)
{
    const int b = blockIdx.x;
    const int tid = threadIdx.x;
    __shared__ float A[SEQ][SEQ + 2];     // pitch 130
    __shared__ float P[SEQ * SEQ];        // pot tile, pitch 128

    // Stage pot[b] into LDS with float4 loads (coalesced).
    {
        const float4* pg = reinterpret_cast<const float4*>(pot + (size_t)b * SEQ * SEQ);
        float4* pl = reinterpret_cast<float4*>(P);
        #pragma unroll
        for (int idx = tid; idx < SEQ * SEQ / 4; idx += 256)
            pl[idx] = pg[idx];
    }
    __syncthreads();

    if (tid < SEQ) A[tid][0] = P[tid * SEQ + tid];
    __syncthreads();

    for (int w = 1; w < SEQ; ++w) {
        const int entries = SEQ - w;
        int tpe = 1;                       // largest pow2 with tpe*entries <= 256
        while (tpe < 64 && (tpe << 1) * entries <= 256) tpe <<= 1;
        const int lt = 31 - __clz(tpe);
        const int i = tid >> lt;           // entry index
        const int s = tid & (tpe - 1);
        float partial = -3.0e38f;
        float pw = 0.0f;
        if (i < entries) {
            pw = P[i * SEQ + i + w];       // LDS broadcast, issued early
            for (int k = s; k < w; k += tpe)
                partial = fmaxf(partial, A[i][k] + A[i + k + 1][w - 1 - k]);
            for (int d = tpe >> 1; d > 0; d >>= 1)
                partial = fmaxf(partial, __shfl_down(partial, d, tpe));
        }
        __syncthreads();                   // everyone reaches this
        if (i < entries && s == 0)
            A[i][w] = partial + pw;
        __syncthreads();
    }

    if (tid == 0) {
        const int len = lenbuf[b];
        const float pred = A[0][len - 1];
        float margin = pred - gold[b];
        margin = margin > 0.0f ? margin : 0.0f;
        atomicAdd(out, margin * (1.0f / (float)BATCH));
    }
}

extern "C" void kernel_launch(void* const* d_in, const int* in_sizes, int n_in,
                              void* d_out, int out_size, void* d_ws, size_t ws_size,
                              hipStream_t stream) {
    const float* logits = (const float*)d_in[0];
    const int* labels = (const int*)d_in[1];
    float* out = (float*)d_out;

    float* pot = (float*)d_ws;                          // B*N*N floats = 4 MB
    float* gold = pot + (size_t)BATCH * SEQ * SEQ;      // B floats
    int* lenbuf = (int*)(gold + BATCH);                 // B ints

    hipMemsetAsync(out, 0, sizeof(float), stream);
    hipMemsetAsync(gold, 0, BATCH * sizeof(float), stream);

    pot_gold_kernel<<<BATCH * SEQ, 256, 0, stream>>>(logits, labels, pot, gold, lenbuf);
    cky_kernel<<<BATCH, 256, 0, stream>>>(pot, gold, lenbuf, out);
}

// Round 4
// 306.750 us; speedup vs baseline: 1.2344x; 1.2344x over previous
//
#include <hip/hip_runtime.h>

#define BATCH 64
#define SEQ   128
#define NLAB  32
#define NEGF  -3.0e38f

// ---------------------------------------------------------------------------
// Kernel 0: lengths. len[b] = count(labels[b,0,:] != -100)
// ---------------------------------------------------------------------------
__global__ __launch_bounds__(64) void len_kernel(
    const int* __restrict__ labels, int* __restrict__ lenbuf)
{
    const int b = blockIdx.x;
    const int t = threadIdx.x;
    const size_t base = (size_t)b * SEQ * SEQ;
    int cnt = (labels[base + t] != -100) + (labels[base + 64 + t] != -100);
    #pragma unroll
    for (int d = 32; d; d >>= 1) cnt += __shfl_down(cnt, d, 64);
    if (t == 0) lenbuf[b] = cnt;
}

// ---------------------------------------------------------------------------
// Kernel 1 (v2): one thread per cell. 8 float4 loads in flight, straight-line
// VALU over 32 labels. No cross-lane traffic except one gold wave-reduce.
//   pot[c] = max_l (logits[c,l]-logits[c,0] + 1 - (l==lab) + special)
//   gold[b] += logits[c,lab]-logits[c,0]
// ---------------------------------------------------------------------------
__global__ __launch_bounds__(256) void pot_gold_kernel(
    const float* __restrict__ logits, const int* __restrict__ labels,
    const int* __restrict__ lenbuf,
    float* __restrict__ pot, float* __restrict__ gold)
{
    const int c = blockIdx.x * 256 + threadIdx.x;   // cell id
    const int b = c >> 14;                          // / (SEQ*SEQ)
    const int ij = c & (SEQ * SEQ - 1);
    const int i = ij >> 7;
    const int j = ij & (SEQ - 1);

    const float4* src = reinterpret_cast<const float4*>(logits) + ((size_t)c << 3);
    float4 f[8];
    #pragma unroll
    for (int t = 0; t < 8; ++t) f[t] = src[t];

    const int lab_raw = labels[c];
    const int lab = lab_raw < 0 ? 0 : lab_raw;
    const int len = lenbuf[b];
    const bool special = (i == 0) && (j == len - 1);

    const float l0 = f[0].x;
    float m = NEGF, g = 0.0f;
    #pragma unroll
    for (int t = 0; t < 8; ++t) {
        const float vv[4] = { f[t].x, f[t].y, f[t].z, f[t].w };
        #pragma unroll
        for (int cc = 0; cc < 4; ++cc) {
            const int l = t * 4 + cc;
            const float r = vv[cc] - l0;
            const bool isg = (l == lab);
            g = isg ? r : g;
            float cand = r + (isg ? 0.0f : 1.0f);
            if (special && l == 0) cand -= 1.0e9f;
            m = fmaxf(m, cand);
        }
    }
    pot[c] = m;

    #pragma unroll
    for (int d = 32; d; d >>= 1) g += __shfl_down(g, d, 64);
    __shared__ float s_red[4];
    if ((threadIdx.x & 63) == 0) s_red[threadIdx.x >> 6] = g;
    __syncthreads();
    if (threadIdx.x == 0)
        atomicAdd(&gold[b], s_red[0] + s_red[1] + s_red[2] + s_red[3]);
}

// ---------------------------------------------------------------------------
// Kernel 2 (v3): max-plus CKY, one block (512 thr) per batch element.
// Two LDS tables, pitch 132 (16B-aligned rows, pads 128..131 stay NEGF):
//   A [i][k] = best span starting at i, width k
//   Bt[j][m] = best span ending  at j, width m   ( == A[j-m][m] )
//   A[i][w]  = pot[i][i+w] + max_{k<w} A[i][k] + Bt[i+w][w-1-k]
// Operand1 read as float4 (k-quads, OOB lanes reg-masked to NEGF);
// operand2 as 4 scalar reads (negative m lands in always-NEGF pad, masked
// anyway). ONE barrier per step: writes go to column w, reads see k<w.
// pot prefetched one step ahead -> global latency off the critical path.
// ---------------------------------------------------------------------------
__global__ __launch_bounds__(512, 1) void cky_kernel(
    const float* __restrict__ pot, const float* __restrict__ gold,
    const int* __restrict__ lenbuf, float* __restrict__ out)
{
    const int b = blockIdx.x;
    const int tid = threadIdx.x;
    const float* p = pot + (size_t)b * SEQ * SEQ;

    constexpr int PITCH = 132;
    __shared__ __align__(16) float S[2 * SEQ * PITCH];   // A then Bt, 135168 B
    float* Abase = S;
    float* Bbase = S + SEQ * PITCH;

    {   // init everything to NEGF (pads must stay NEGF forever)
        const float4 neg4 = make_float4(NEGF, NEGF, NEGF, NEGF);
        float4* s4 = reinterpret_cast<float4*>(S);
        for (int idx = tid; idx < 2 * SEQ * PITCH / 4; idx += 512) s4[idx] = neg4;
    }
    __syncthreads();
    if (tid < SEQ) {
        const float term = p[tid * (SEQ + 1)];
        Abase[tid * PITCH] = term;
        Bbase[tid * PITCH] = term;
    }
    __syncthreads();

    // prefetch pot for w = 1
    float potv;
    {
        int e1 = SEQ - 1;
        int i1 = tid >> 2;            // tpe(1) = 4
        if (i1 >= e1) i1 = e1 - 1;
        potv = p[i1 * (SEQ + 1) + 1];
    }

    for (int w = 1; w < SEQ; ++w) {
        const int entries = SEQ - w;
        int tpe = 1, lt = 0;
        while (tpe < 64 && ((tpe << 1) * entries) <= 512) { tpe <<= 1; ++lt; }
        const int i = tid >> lt;
        const int s = tid & (tpe - 1);

        // prefetch next step's pot (independent of this step's LDS work)
        float pot_next = 0.0f;
        if (w + 1 < SEQ) {
            const int e2 = SEQ - (w + 1);
            int tpe2 = 1, lt2 = 0;
            while (tpe2 < 64 && ((tpe2 << 1) * e2) <= 512) { tpe2 <<= 1; ++lt2; }
            int i2 = tid >> lt2;
            if (i2 >= e2) i2 = e2 - 1;
            pot_next = p[i2 * (SEQ + 1) + (w + 1)];
        }

        if (i < entries) {
            float* Arow = Abase + i * PITCH;
            float* Brow = Bbase + (i + w) * PITCH;
            const int wq = (w + 3) >> 2;         // k-quads covering [0, 4*wq)
            float m = NEGF;
            int q = s;
            // unroll x2: both quads' 10 LDS loads issued before any use
            for (; q + tpe < wq; q += 2 * tpe) {
                const int k0 = q << 2, k1 = (q + tpe) << 2;
                float4 a0 = *reinterpret_cast<const float4*>(Arow + k0);
                float4 a1 = *reinterpret_cast<const float4*>(Arow + k1);
                const float b00 = Brow[w - 1 - k0], b01 = Brow[w - 2 - k0],
                            b02 = Brow[w - 3 - k0], b03 = Brow[w - 4 - k0];
                const float b10 = Brow[w - 1 - k1], b11 = Brow[w - 2 - k1],
                            b12 = Brow[w - 3 - k1], b13 = Brow[w - 4 - k1];
                if (k1 + 4 > w) {   // only possible on the second quad
                    a1.y = (k1 + 1 < w) ? a1.y : NEGF;
                    a1.z = (k1 + 2 < w) ? a1.z : NEGF;
                    a1.w = (k1 + 3 < w) ? a1.w : NEGF;
                }
                m = fmaxf(m, fmaxf(fmaxf(a0.x + b00, a0.y + b01),
                                   fmaxf(a0.z + b02, a0.w + b03)));
                m = fmaxf(m, fmaxf(fmaxf(a1.x + b10, a1.y + b11),
                                   fmaxf(a1.z + b12, a1.w + b13)));
            }
            if (q < wq) {
                const int k0 = q << 2;
                float4 a0 = *reinterpret_cast<const float4*>(Arow + k0);
                const float b00 = Brow[w - 1 - k0], b01 = Brow[w - 2 - k0],
                            b02 = Brow[w - 3 - k0], b03 = Brow[w - 4 - k0];
                if (k0 + 4 > w) {
                    a0.y = (k0 + 1 < w) ? a0.y : NEGF;
                    a0.z = (k0 + 2 < w) ? a0.z : NEGF;
                    a0.w = (k0 + 3 < w) ? a0.w : NEGF;
                }
                m = fmaxf(m, fmaxf(fmaxf(a0.x + b00, a0.y + b01),
                                   fmaxf(a0.z + b02, a0.w + b03)));
            }
            for (int d = tpe >> 1; d; d >>= 1)
                m = fmaxf(m, __shfl_down(m, d, tpe));
            if (s == 0) {
                const float val = m + potv;
                Arow[w] = val;
                Brow[w] = val;
            }
        }
        potv = pot_next;
        __syncthreads();
    }

    if (tid == 0) {
        const int len = lenbuf[b];
        const float pred = Abase[len - 1];        // A[0][len-1]
        float margin = pred - gold[b];
        margin = margin > 0.0f ? margin : 0.0f;
        atomicAdd(out, margin * (1.0f / (float)BATCH));
    }
}

extern "C" void kernel_launch(void* const* d_in, const int* in_sizes, int n_in,
                              void* d_out, int out_size, void* d_ws, size_t ws_size,
                              hipStream_t stream) {
    const float* logits = (const float*)d_in[0];
    const int* labels = (const int*)d_in[1];
    float* out = (float*)d_out;

    float* pot = (float*)d_ws;                          // B*N*N floats = 4 MB
    float* gold = pot + (size_t)BATCH * SEQ * SEQ;      // B floats
    int* lenbuf = (int*)(gold + BATCH);                 // B ints

    (void)hipMemsetAsync(out, 0, sizeof(float), stream);
    (void)hipMemsetAsync(gold, 0, BATCH * sizeof(float), stream);

    len_kernel<<<BATCH, 64, 0, stream>>>(labels, lenbuf);
    pot_gold_kernel<<<BATCH * SEQ * SEQ / 256, 256, 0, stream>>>(
        logits, labels, lenbuf, pot, gold);
    cky_kernel<<<BATCH, 512, 0, stream>>>(pot, gold, lenbuf, out);
}

// Round 5
// 302.010 us; speedup vs baseline: 1.2537x; 1.0157x over previous
//
#include <hip/hip_runtime.h>

#define BATCH 64
#define SEQ   128
#define NLAB  32
#define NEGF  -3.0e38f

// ---------------------------------------------------------------------------
// Kernel 0: lengths. len[b] = count(labels[b,0,:] != -100)
// ---------------------------------------------------------------------------
__global__ __launch_bounds__(64) void len_kernel(
    const int* __restrict__ labels, int* __restrict__ lenbuf)
{
    const int b = blockIdx.x;
    const int t = threadIdx.x;
    const size_t base = (size_t)b * SEQ * SEQ;
    int cnt = (labels[base + t] != -100) + (labels[base + 64 + t] != -100);
    #pragma unroll
    for (int d = 32; d; d >>= 1) cnt += __shfl_down(cnt, d, 64);
    if (t == 0) lenbuf[b] = cnt;
}

// ---------------------------------------------------------------------------
// Kernel 1 (v3): coalesced loads + wave-private LDS transpose, 4 lanes/cell.
// Each wave: chunk = 16 cells. Global reads are lane-contiguous float4
// (1 KB/instr, ideal). LDS pitch 36 floats: write bank-quads (c+t)%8 optimal;
// read bank-quads (c+2u)%8 -> 2-way (free). Same-wave DS ordering makes
// barriers unnecessary (regions are wave-private).
// ---------------------------------------------------------------------------
__global__ __launch_bounds__(256) void pot_gold_kernel(
    const float* __restrict__ logits, const int* __restrict__ labels,
    const int* __restrict__ lenbuf,
    float* __restrict__ pot, float* __restrict__ gold)
{
    const int tid = threadIdx.x;
    const int wave = tid >> 6, lane = tid & 63;
    __shared__ __align__(16) float LP[4 * 16 * 36];   // 9216 B
    float* W = LP + wave * (16 * 36);

    const int block_cell0 = blockIdx.x * 256;         // 256 cells per block
    const int b = block_cell0 >> 14;
    const int len = lenbuf[b];
    float gacc = 0.0f;

    const int wave_cell0 = block_cell0 + wave * 64;

    #pragma unroll
    for (int chunk = 0; chunk < 4; ++chunk) {
        const int c0 = wave_cell0 + chunk * 16;       // 16 cells this chunk
        const float4* src = reinterpret_cast<const float4*>(logits) + ((size_t)c0 << 3);
        const float4 f0 = src[lane];
        const float4 f1 = src[lane + 64];
        const int lv = (lane < 16) ? labels[c0 + lane] : 0;

        {   // scatter to LDS: quad q -> cell q>>3, slot q&7
            const int cA = lane >> 3, tA = lane & 7;
            *reinterpret_cast<float4*>(W + cA * 36 + tA * 4) = f0;
            const int q1 = lane + 64;
            const int cB = q1 >> 3, tB = q1 & 7;
            *reinterpret_cast<float4*>(W + cB * 36 + tB * 4) = f1;
        }
        // same-wave DS ops are in-order; compiler can't reorder may-alias LDS.
        const int c = lane >> 2, u = lane & 3;        // cell, quarter
        const float4 r0 = *reinterpret_cast<const float4*>(W + c * 36 + u * 8);
        const float4 r1 = *reinterpret_cast<const float4*>(W + c * 36 + u * 8 + 4);

        int lab = __shfl(lv, c, 64);
        if (lab < 0) lab = 0;
        const float l0 = __shfl(r0.x, c << 2, 64);    // logits[cell][0]

        const int cell = c0 + c;
        const int ci = (cell >> 7) & (SEQ - 1);
        const int cj = cell & (SEQ - 1);
        const bool special = (ci == 0) && (cj == len - 1);

        const float vv[8] = { r0.x, r0.y, r0.z, r0.w, r1.x, r1.y, r1.z, r1.w };
        float m = NEGF, g = 0.0f;
        #pragma unroll
        for (int e = 0; e < 8; ++e) {
            const int l = u * 8 + e;
            const float r = vv[e] - l0;
            const bool isg = (l == lab);
            g = isg ? r : g;
            float cand = r + (isg ? 0.0f : 1.0f);
            if (l == 0 && special) cand -= 1.0e9f;
            m = fmaxf(m, cand);
        }
        m = fmaxf(m, __shfl_xor(m, 1, 64));
        m = fmaxf(m, __shfl_xor(m, 2, 64));
        g += __shfl_xor(g, 1, 64);
        g += __shfl_xor(g, 2, 64);
        if (u == 0) {
            pot[cell] = m;
            gacc += g;
        }
    }

    #pragma unroll
    for (int d = 1; d < 64; d <<= 1) gacc += __shfl_xor(gacc, d, 64);
    __shared__ float gred[4];
    if (lane == 0) gred[wave] = gacc;
    __syncthreads();
    if (tid == 0)
        atomicAdd(&gold[b], gred[0] + gred[1] + gred[2] + gred[3]);
}

// ---------------------------------------------------------------------------
// Kernel 2 (v4): max-plus CKY, one block (512 thr) per batch element.
//   A [i][k] row-major pitch 132 : best span starting at i, width k
//   Bt[m][j] WIDTH-major pitch 129: best span ending at j, width m
//   A[i][w] = pot[i][i+w] + max_{k<w} A[i][k] + Bt[w-1-k][i+w]
// pot lives IN the tables: slot (i,w)/(w,j) holds pot until step w overwrites
// it -> zero global traffic in the loop, barrier drains nothing.
// Bank math: A float4 reads quad-bank (i+q)%8 (~2x min, ok);
// Bt scalar reads bank (i-4s+const)%32 (~2-way, free); writes near-perfect.
// ---------------------------------------------------------------------------
__global__ __launch_bounds__(512, 1) void cky_kernel(
    const float* __restrict__ pot, const float* __restrict__ gold,
    const int* __restrict__ lenbuf, float* __restrict__ out)
{
    const int b = blockIdx.x;
    const int tid = threadIdx.x;
    const float* p = pot + (size_t)b * SEQ * SEQ;

    __shared__ __align__(16) float A[SEQ * 132];      // 67584 B
    __shared__ __align__(16) float Bt[SEQ * 129];     // 66048 B

    {   // NEGF-fill A (masking safety net for the float4 overshoot region)
        const float4 neg4 = make_float4(NEGF, NEGF, NEGF, NEGF);
        float4* a4 = reinterpret_cast<float4*>(A);
        for (int idx = tid; idx < SEQ * 132 / 4; idx += 512) a4[idx] = neg4;
    }
    __syncthreads();
    {   // scatter pot into both tables (coalesced global float4 reads)
        const float4* p4 = reinterpret_cast<const float4*>(p);
        for (int qi = tid; qi < SEQ * SEQ / 4; qi += 512) {
            const int i = qi >> 5;
            const int j0 = (qi & 31) << 2;
            const float4 v = p4[qi];
            const float vv[4] = { v.x, v.y, v.z, v.w };
            #pragma unroll
            for (int c2 = 0; c2 < 4; ++c2) {
                const int j = j0 + c2;
                if (j >= i) {
                    A[i * 132 + (j - i)] = vv[c2];
                    Bt[(j - i) * 129 + j] = vv[c2];
                }
            }
        }
    }
    __syncthreads();

    for (int w = 1; w < SEQ; ++w) {
        const int entries = SEQ - w;
        int tpe = 1, lt = 0;                  // tpe >= 4 always (entries<=127)
        while (tpe < 64 && ((tpe << 1) * entries) <= 512) { tpe <<= 1; ++lt; }
        const int i = tid >> lt;
        const int s = tid & (tpe - 1);

        if (i < entries) {
            float* Arow = A + i * 132;
            const int j = i + w;
            const float potv = Arow[w];       // pot[i][i+w], untouched til now
            const int wq = (w + 3) >> 2;
            float m = NEGF;
            int q = s;
            for (; q + tpe < wq; q += 2 * tpe) {
                const int k0 = q << 2, k1 = (q + tpe) << 2;
                const float4 a0 = *reinterpret_cast<const float4*>(Arow + k0);
                float4 a1 = *reinterpret_cast<const float4*>(Arow + k1);
                // first quad: k0+4 <= w-13, no masks/clamps needed
                const float b00 = Bt[(w - 1 - k0) * 129 + j];
                const float b01 = Bt[(w - 2 - k0) * 129 + j];
                const float b02 = Bt[(w - 3 - k0) * 129 + j];
                const float b03 = Bt[(w - 4 - k0) * 129 + j];
                // second quad: k1 <= w-1; rows below 0 clamp, values masked
                const int r1 = w - 1 - k1;
                const float b10 = Bt[r1 * 129 + j];
                const float b11 = Bt[(r1 > 1 ? r1 - 1 : 0) * 129 + j];
                const float b12 = Bt[(r1 > 2 ? r1 - 2 : 0) * 129 + j];
                const float b13 = Bt[(r1 > 3 ? r1 - 3 : 0) * 129 + j];
                if (k1 + 4 > w) {
                    a1.y = (k1 + 1 < w) ? a1.y : NEGF;
                    a1.z = (k1 + 2 < w) ? a1.z : NEGF;
                    a1.w = (k1 + 3 < w) ? a1.w : NEGF;
                }
                m = fmaxf(m, fmaxf(fmaxf(a0.x + b00, a0.y + b01),
                                   fmaxf(a0.z + b02, a0.w + b03)));
                m = fmaxf(m, fmaxf(fmaxf(a1.x + b10, a1.y + b11),
                                   fmaxf(a1.z + b12, a1.w + b13)));
            }
            if (q < wq) {
                const int k0 = q << 2;
                float4 a0 = *reinterpret_cast<const float4*>(Arow + k0);
                const int r0 = w - 1 - k0;    // >= 0 since k0 <= w-1
                const float b00 = Bt[r0 * 129 + j];
                const float b01 = Bt[(r0 > 1 ? r0 - 1 : 0) * 129 + j];
                const float b02 = Bt[(r0 > 2 ? r0 - 2 : 0) * 129 + j];
                const float b03 = Bt[(r0 > 3 ? r0 - 3 : 0) * 129 + j];
                if (k0 + 4 > w) {
                    a0.y = (k0 + 1 < w) ? a0.y : NEGF;
                    a0.z = (k0 + 2 < w) ? a0.z : NEGF;
                    a0.w = (k0 + 3 < w) ? a0.w : NEGF;
                }
                m = fmaxf(m, fmaxf(fmaxf(a0.x + b00, a0.y + b01),
                                   fmaxf(a0.z + b02, a0.w + b03)));
            }
            for (int d = tpe >> 1; d; d >>= 1)
                m = fmaxf(m, __shfl_down(m, d, tpe));
            if (s == 0) {
                const float val = m + potv;
                Arow[w] = val;
                Bt[w * 129 + j] = val;
            }
        }
        __syncthreads();
    }

    if (tid == 0) {
        const int len = lenbuf[b];
        const float pred = A[len - 1];        // A[0][len-1]
        float margin = pred - gold[b];
        margin = margin > 0.0f ? margin : 0.0f;
        atomicAdd(out, margin * (1.0f / (float)BATCH));
    }
}

extern "C" void kernel_launch(void* const* d_in, const int* in_sizes, int n_in,
                              void* d_out, int out_size, void* d_ws, size_t ws_size,
                              hipStream_t stream) {
    const float* logits = (const float*)d_in[0];
    const int* labels = (const int*)d_in[1];
    float* out = (float*)d_out;

    float* pot = (float*)d_ws;                          // B*N*N floats = 4 MB
    float* gold = pot + (size_t)BATCH * SEQ * SEQ;      // B floats
    int* lenbuf = (int*)(gold + BATCH);                 // B ints

    (void)hipMemsetAsync(out, 0, sizeof(float), stream);
    (void)hipMemsetAsync(gold, 0, BATCH * sizeof(float), stream);

    len_kernel<<<BATCH, 64, 0, stream>>>(labels, lenbuf);
    pot_gold_kernel<<<BATCH * SEQ * SEQ / 256, 256, 0, stream>>>(
        logits, labels, lenbuf, pot, gold);
    cky_kernel<<<BATCH, 512, 0, stream>>>(pot, gold, lenbuf, out);
}

// Round 6
// 267.857 us; speedup vs baseline: 1.4136x; 1.1275x over previous
//
#include <hip/hip_runtime.h>

#define BATCH 64
#define SEQ   128
#define NLAB  32
#define NEGF  -3.0e38f

// ---------------------------------------------------------------------------
// Kernel 0: lengths. len[b] = count(labels[b,0,:] != -100)
// ---------------------------------------------------------------------------
__global__ __launch_bounds__(64) void len_kernel(
    const int* __restrict__ labels, int* __restrict__ lenbuf)
{
    const int b = blockIdx.x;
    const int t = threadIdx.x;
    const size_t base = (size_t)b * SEQ * SEQ;
    int cnt = (labels[base + t] != -100) + (labels[base + 64 + t] != -100);
    #pragma unroll
    for (int d = 32; d; d >>= 1) cnt += __shfl_down(cnt, d, 64);
    if (t == 0) lenbuf[b] = cnt;
}

// ---------------------------------------------------------------------------
// Kernel 1 (v3): coalesced loads + wave-private LDS transpose, 4 lanes/cell.
// ---------------------------------------------------------------------------
__global__ __launch_bounds__(256) void pot_gold_kernel(
    const float* __restrict__ logits, const int* __restrict__ labels,
    const int* __restrict__ lenbuf,
    float* __restrict__ pot, float* __restrict__ gold)
{
    const int tid = threadIdx.x;
    const int wave = tid >> 6, lane = tid & 63;
    __shared__ __align__(16) float LP[4 * 16 * 36];   // 9216 B
    float* W = LP + wave * (16 * 36);

    const int block_cell0 = blockIdx.x * 256;         // 256 cells per block
    const int b = block_cell0 >> 14;
    const int len = lenbuf[b];
    float gacc = 0.0f;

    const int wave_cell0 = block_cell0 + wave * 64;

    #pragma unroll
    for (int chunk = 0; chunk < 4; ++chunk) {
        const int c0 = wave_cell0 + chunk * 16;       // 16 cells this chunk
        const float4* src = reinterpret_cast<const float4*>(logits) + ((size_t)c0 << 3);
        const float4 f0 = src[lane];
        const float4 f1 = src[lane + 64];
        const int lv = (lane < 16) ? labels[c0 + lane] : 0;

        {   // scatter to LDS: quad q -> cell q>>3, slot q&7
            const int cA = lane >> 3, tA = lane & 7;
            *reinterpret_cast<float4*>(W + cA * 36 + tA * 4) = f0;
            const int q1 = lane + 64;
            const int cB = q1 >> 3, tB = q1 & 7;
            *reinterpret_cast<float4*>(W + cB * 36 + tB * 4) = f1;
        }
        const int c = lane >> 2, u = lane & 3;        // cell, quarter
        const float4 r0 = *reinterpret_cast<const float4*>(W + c * 36 + u * 8);
        const float4 r1 = *reinterpret_cast<const float4*>(W + c * 36 + u * 8 + 4);

        int lab = __shfl(lv, c, 64);
        if (lab < 0) lab = 0;
        const float l0 = __shfl(r0.x, c << 2, 64);    // logits[cell][0]

        const int cell = c0 + c;
        const int ci = (cell >> 7) & (SEQ - 1);
        const int cj = cell & (SEQ - 1);
        const bool special = (ci == 0) && (cj == len - 1);

        const float vv[8] = { r0.x, r0.y, r0.z, r0.w, r1.x, r1.y, r1.z, r1.w };
        float m = NEGF, g = 0.0f;
        #pragma unroll
        for (int e = 0; e < 8; ++e) {
            const int l = u * 8 + e;
            const float r = vv[e] - l0;
            const bool isg = (l == lab);
            g = isg ? r : g;
            float cand = r + (isg ? 0.0f : 1.0f);
            if (l == 0 && special) cand -= 1.0e9f;
            m = fmaxf(m, cand);
        }
        m = fmaxf(m, __shfl_xor(m, 1, 64));
        m = fmaxf(m, __shfl_xor(m, 2, 64));
        g += __shfl_xor(g, 1, 64);
        g += __shfl_xor(g, 2, 64);
        if (u == 0) {
            pot[cell] = m;
            gacc += g;
        }
    }

    #pragma unroll
    for (int d = 1; d < 64; d <<= 1) gacc += __shfl_xor(gacc, d, 64);
    __shared__ float gred[4];
    if (lane == 0) gred[wave] = gacc;
    __syncthreads();
    if (tid == 0)
        atomicAdd(&gold[b], gred[0] + gred[1] + gred[2] + gred[3]);
}

// ---------------------------------------------------------------------------
// Kernel 2 (v5): max-plus CKY, compile-time phase-specialized steps.
//   A [i][k] row-major pitch 132 : best span starting at i, width k
//   Bt[m][j] width-major pitch 130: best span ending at j, width m
//   A[i][w] = pot[i][i+w] + max_{k<w} A[i][k] + Bt[w-1-k][i+w]
// pot lives IN the tables until overwritten. TPE chosen small (shuffles are
// latency-serial; quads/lane are pipelined): Q<=4 quads/lane, TPE<=8.
// Bt pitch 130 -> scalar-read bank = i-2*TPE*s+c : max 2-way (free).
// All loops have compile-time trip bounds; one barrier per step.
// ---------------------------------------------------------------------------
template<int TPE, int LT>
__device__ __forceinline__ void cky_step(
    float* __restrict__ A, float* __restrict__ Bt, const int w, const int tid)
{
    const int entries = SEQ - w;
    const int i = tid >> LT;
    const int s = tid & (TPE - 1);
    if (i < entries) {
        float* Arow = A + i * 132;
        const int j = i + w;
        const float potv = Arow[w];          // pot[i][i+w], untouched til now
        const int wq = (w + 3) >> 2;
        float m = NEGF;
        #pragma unroll 4
        for (int q = s; q < wq; q += TPE) {
            const int k0 = q << 2;
            float4 a = *reinterpret_cast<const float4*>(Arow + k0);
            const int r0 = w - 1 - k0;       // >= 0 always (k0 <= w-1)
            const float b0 = Bt[r0 * 130 + j];
            const float b1 = Bt[(r0 > 1 ? r0 - 1 : 0) * 130 + j];
            const float b2 = Bt[(r0 > 2 ? r0 - 2 : 0) * 130 + j];
            const float b3 = Bt[(r0 > 3 ? r0 - 3 : 0) * 130 + j];
            a.y = (k0 + 1 < w) ? a.y : NEGF;
            a.z = (k0 + 2 < w) ? a.z : NEGF;
            a.w = (k0 + 3 < w) ? a.w : NEGF;
            m = fmaxf(m, fmaxf(fmaxf(a.x + b0, a.y + b1),
                               fmaxf(a.z + b2, a.w + b3)));
        }
        #pragma unroll
        for (int d = TPE >> 1; d; d >>= 1)
            m = fmaxf(m, __shfl_down(m, d, TPE));
        if (s == 0) {
            const float val = m + potv;
            Arow[w] = val;
            Bt[w * 130 + j] = val;
        }
    }
    __syncthreads();
}

__global__ __launch_bounds__(512, 1) void cky_kernel(
    const float* __restrict__ pot, const float* __restrict__ gold,
    const int* __restrict__ lenbuf, float* __restrict__ out)
{
    const int b = blockIdx.x;
    const int tid = threadIdx.x;
    const float* p = pot + (size_t)b * SEQ * SEQ;

    __shared__ __align__(16) float A[SEQ * 132];      // 67584 B
    __shared__ __align__(16) float Bt[SEQ * 130];     // 66560 B

    {   // NEGF-fill A (safety net for masked float4 overshoot region)
        const float4 neg4 = make_float4(NEGF, NEGF, NEGF, NEGF);
        float4* a4 = reinterpret_cast<float4*>(A);
        for (int idx = tid; idx < SEQ * 132 / 4; idx += 512) a4[idx] = neg4;
    }
    __syncthreads();
    {   // scatter pot into both tables (coalesced global float4 reads)
        const float4* p4 = reinterpret_cast<const float4*>(p);
        for (int qi = tid; qi < SEQ * SEQ / 4; qi += 512) {
            const int i = qi >> 5;
            const int j0 = (qi & 31) << 2;
            const float4 v = p4[qi];
            const float vv[4] = { v.x, v.y, v.z, v.w };
            #pragma unroll
            for (int c2 = 0; c2 < 4; ++c2) {
                const int j = j0 + c2;
                if (j >= i) {
                    A[i * 132 + (j - i)] = vv[c2];
                    Bt[(j - i) * 130 + j] = vv[c2];
                }
            }
        }
    }
    __syncthreads();

    // Phase schedule: Q = ceil(wq/TPE) <= 4 everywhere; entries*TPE <= 512.
    for (int w = 1;  w < 16;  ++w) cky_step<1, 0>(A, Bt, w, tid);
    for (int w = 16; w < 32;  ++w) cky_step<2, 1>(A, Bt, w, tid);
    for (int w = 32; w < 64;  ++w) cky_step<4, 2>(A, Bt, w, tid);
    for (int w = 64; w < SEQ; ++w) cky_step<8, 3>(A, Bt, w, tid);

    if (tid == 0) {
        const int len = lenbuf[b];
        const float pred = A[len - 1];        // A[0][len-1]
        float margin = pred - gold[b];
        margin = margin > 0.0f ? margin : 0.0f;
        atomicAdd(out, margin * (1.0f / (float)BATCH));
    }
}

extern "C" void kernel_launch(void* const* d_in, const int* in_sizes, int n_in,
                              void* d_out, int out_size, void* d_ws, size_t ws_size,
                              hipStream_t stream) {
    const float* logits = (const float*)d_in[0];
    const int* labels = (const int*)d_in[1];
    float* out = (float*)d_out;

    float* pot = (float*)d_ws;                          // B*N*N floats = 4 MB
    float* gold = pot + (size_t)BATCH * SEQ * SEQ;      // B floats
    int* lenbuf = (int*)(gold + BATCH);                 // B ints

    (void)hipMemsetAsync(out, 0, sizeof(float), stream);
    (void)hipMemsetAsync(gold, 0, BATCH * sizeof(float), stream);

    len_kernel<<<BATCH, 64, 0, stream>>>(labels, lenbuf);
    pot_gold_kernel<<<BATCH * SEQ * SEQ / 256, 256, 0, stream>>>(
        logits, labels, lenbuf, pot, gold);
    cky_kernel<<<BATCH, 512, 0, stream>>>(pot, gold, lenbuf, out);
}

// Round 7
// 261.711 us; speedup vs baseline: 1.4468x; 1.0235x over previous
//
#include <hip/hip_runtime.h>

#define BATCH 64
#define SEQ   128
#define NLAB  32
#define NEGF  -3.0e38f

// ---------------------------------------------------------------------------
// Kernel 0: lengths + gold-accumulator zeroing.
// ---------------------------------------------------------------------------
__global__ __launch_bounds__(64) void len_kernel(
    const int* __restrict__ labels, int* __restrict__ lenbuf,
    float* __restrict__ gold)
{
    const int b = blockIdx.x;
    const int t = threadIdx.x;
    const size_t base = (size_t)b * SEQ * SEQ;
    int cnt = (labels[base + t] != -100) + (labels[base + 64 + t] != -100);
    #pragma unroll
    for (int d = 32; d; d >>= 1) cnt += __shfl_down(cnt, d, 64);
    if (t == 0) { lenbuf[b] = cnt; gold[b] = 0.0f; }
}

// ---------------------------------------------------------------------------
// Kernel 1 (v3): coalesced loads + wave-private LDS transpose, 4 lanes/cell.
// ---------------------------------------------------------------------------
__global__ __launch_bounds__(256) void pot_gold_kernel(
    const float* __restrict__ logits, const int* __restrict__ labels,
    const int* __restrict__ lenbuf,
    float* __restrict__ pot, float* __restrict__ gold)
{
    const int tid = threadIdx.x;
    const int wave = tid >> 6, lane = tid & 63;
    __shared__ __align__(16) float LP[4 * 16 * 36];   // 9216 B
    float* W = LP + wave * (16 * 36);

    const int block_cell0 = blockIdx.x * 256;         // 256 cells per block
    const int b = block_cell0 >> 14;
    const int len = lenbuf[b];
    float gacc = 0.0f;

    const int wave_cell0 = block_cell0 + wave * 64;

    #pragma unroll
    for (int chunk = 0; chunk < 4; ++chunk) {
        const int c0 = wave_cell0 + chunk * 16;       // 16 cells this chunk
        const float4* src = reinterpret_cast<const float4*>(logits) + ((size_t)c0 << 3);
        const float4 f0 = src[lane];
        const float4 f1 = src[lane + 64];
        const int lv = (lane < 16) ? labels[c0 + lane] : 0;

        {   // scatter to LDS: quad q -> cell q>>3, slot q&7
            const int cA = lane >> 3, tA = lane & 7;
            *reinterpret_cast<float4*>(W + cA * 36 + tA * 4) = f0;
            const int q1 = lane + 64;
            const int cB = q1 >> 3, tB = q1 & 7;
            *reinterpret_cast<float4*>(W + cB * 36 + tB * 4) = f1;
        }
        const int c = lane >> 2, u = lane & 3;        // cell, quarter
        const float4 r0 = *reinterpret_cast<const float4*>(W + c * 36 + u * 8);
        const float4 r1 = *reinterpret_cast<const float4*>(W + c * 36 + u * 8 + 4);

        int lab = __shfl(lv, c, 64);
        if (lab < 0) lab = 0;
        const float l0 = __shfl(r0.x, c << 2, 64);    // logits[cell][0]

        const int cell = c0 + c;
        const int ci = (cell >> 7) & (SEQ - 1);
        const int cj = cell & (SEQ - 1);
        const bool special = (ci == 0) && (cj == len - 1);

        const float vv[8] = { r0.x, r0.y, r0.z, r0.w, r1.x, r1.y, r1.z, r1.w };
        float m = NEGF, g = 0.0f;
        #pragma unroll
        for (int e = 0; e < 8; ++e) {
            const int l = u * 8 + e;
            const float r = vv[e] - l0;
            const bool isg = (l == lab);
            g = isg ? r : g;
            float cand = r + (isg ? 0.0f : 1.0f);
            if (l == 0 && special) cand -= 1.0e9f;
            m = fmaxf(m, cand);
        }
        m = fmaxf(m, __shfl_xor(m, 1, 64));
        m = fmaxf(m, __shfl_xor(m, 2, 64));
        g += __shfl_xor(g, 1, 64);
        g += __shfl_xor(g, 2, 64);
        if (u == 0) {
            pot[cell] = m;
            gacc += g;
        }
    }

    #pragma unroll
    for (int d = 1; d < 64; d <<= 1) gacc += __shfl_xor(gacc, d, 64);
    __shared__ float gred[4];
    if (lane == 0) gred[wave] = gacc;
    __syncthreads();
    if (tid == 0)
        atomicAdd(&gold[b], gred[0] + gred[1] + gred[2] + gred[3]);
}

// ---------------------------------------------------------------------------
// Kernel 2 (v6): max-plus CKY with contiguous BOTH-operand reads.
//   A [i][k] pitch 132 : best span starting at i, width k (holds pot til step k)
//   Bt[j][c] pitch 132 : c = N-1-width  ->  at step w, k maps to c = N-w+k
//                        (CONTIGUOUS ascending in k — the torch_struct trick)
//   A[i][w] = pot[i][i+w] + max_{k<w} A[i][k] + Bt[i+w][N-w+k]
// B quad alignment c0 ≡ (-w)&3 =: S handled by compile-time template:
//   S0: b128   S2: b64+b64   S1/S3: b32+b64+b32
// Overshoot k>=w: A components masked to NEGF; B lands in NEGF pad cols
// 128..131. One barrier per step; zero global traffic in the loop.
// ---------------------------------------------------------------------------
template<int TPE, int LT, int S>
__device__ __forceinline__ void cky_step(
    float* __restrict__ A, float* __restrict__ Bt, const int w, const int tid)
{
    const int entries = SEQ - w;
    const int i = tid >> LT;
    const int s = tid & (TPE - 1);
    if (i < entries) {
        float* Arow = A + i * 132;
        const int j = i + w;
        const float* Brow = Bt + j * 132 + (SEQ - w);  // index by k directly
        const float potv = Arow[w];          // pot[i][i+w], untouched til now
        const int wq = (w + 3) >> 2;
        float m = NEGF;
        #pragma unroll 4
        for (int q = s; q < wq; q += TPE) {
            const int k0 = q << 2;
            float4 a = *reinterpret_cast<const float4*>(Arow + k0);
            const float* bp = Brow + k0;     // float-addr ≡ S (mod 4)
            float b0, b1, b2, b3;
            if (S == 0) {
                const float4 bv = *reinterpret_cast<const float4*>(bp);
                b0 = bv.x; b1 = bv.y; b2 = bv.z; b3 = bv.w;
            } else if (S == 2) {
                const float2 u0 = *reinterpret_cast<const float2*>(bp);
                const float2 u1 = *reinterpret_cast<const float2*>(bp + 2);
                b0 = u0.x; b1 = u0.y; b2 = u1.x; b3 = u1.y;
            } else {                         // S==1: bp+1 ≡2 ; S==3: bp+1 ≡0
                b0 = bp[0];
                const float2 u = *reinterpret_cast<const float2*>(bp + 1);
                b1 = u.x; b2 = u.y;
                b3 = bp[3];
            }
            a.y = (k0 + 1 < w) ? a.y : NEGF;
            a.z = (k0 + 2 < w) ? a.z : NEGF;
            a.w = (k0 + 3 < w) ? a.w : NEGF;
            m = fmaxf(m, fmaxf(fmaxf(a.x + b0, a.y + b1),
                               fmaxf(a.z + b2, a.w + b3)));
        }
        #pragma unroll
        for (int d = TPE >> 1; d; d >>= 1)
            m = fmaxf(m, __shfl_down(m, d, TPE));
        if (s == 0) {
            const float val = m + potv;
            Arow[w] = val;
            Bt[j * 132 + (SEQ - 1 - w)] = val;
        }
    }
    __syncthreads();
}

template<int TPE, int LT>
__device__ __forceinline__ void cky_phase4(
    float* __restrict__ A, float* __restrict__ Bt, const int w, const int tid)
{   // w ≡ 0 (mod 4): S cycles 0,3,2,1
    cky_step<TPE, LT, 0>(A, Bt, w,     tid);
    cky_step<TPE, LT, 3>(A, Bt, w + 1, tid);
    cky_step<TPE, LT, 2>(A, Bt, w + 2, tid);
    cky_step<TPE, LT, 1>(A, Bt, w + 3, tid);
}

__global__ __launch_bounds__(512, 1) void cky_kernel(
    const float* __restrict__ pot, const float* __restrict__ gold,
    const int* __restrict__ lenbuf, float* __restrict__ out)
{
    const int b = blockIdx.x;
    const int tid = threadIdx.x;
    const float* p = pot + (size_t)b * SEQ * SEQ;

    __shared__ __align__(16) float A[SEQ * 132];      // 67584 B
    __shared__ __align__(16) float Bt[SEQ * 132];     // 67584 B

    {   // NEGF-fill both tables (pads must read as ~NEGF)
        const float4 neg4 = make_float4(NEGF, NEGF, NEGF, NEGF);
        float4* a4 = reinterpret_cast<float4*>(A);
        float4* b4 = reinterpret_cast<float4*>(Bt);
        for (int idx = tid; idx < SEQ * 132 / 4; idx += 512) {
            a4[idx] = neg4; b4[idx] = neg4;
        }
    }
    __syncthreads();
    {   // scatter pot into both tables (coalesced global float4 reads)
        const float4* p4 = reinterpret_cast<const float4*>(p);
        for (int qi = tid; qi < SEQ * SEQ / 4; qi += 512) {
            const int i = qi >> 5;
            const int j0 = (qi & 31) << 2;
            const float4 v = p4[qi];
            const float vv[4] = { v.x, v.y, v.z, v.w };
            #pragma unroll
            for (int c2 = 0; c2 < 4; ++c2) {
                const int j = j0 + c2;
                if (j >= i) {
                    A[i * 132 + (j - i)] = vv[c2];
                    Bt[j * 132 + (SEQ - 1 - (j - i))] = vv[c2];
                }
            }
        }
    }
    __syncthreads();

    // Phase schedule: Q = ceil(wq/TPE) <= 4 everywhere; entries*TPE <= 512.
    cky_step<1, 0, 3>(A, Bt, 1, tid);
    cky_step<1, 0, 2>(A, Bt, 2, tid);
    cky_step<1, 0, 1>(A, Bt, 3, tid);
    for (int w = 4;  w < 16;  w += 4) cky_phase4<1, 0>(A, Bt, w, tid);
    for (int w = 16; w < 32;  w += 4) cky_phase4<2, 1>(A, Bt, w, tid);
    for (int w = 32; w < 64;  w += 4) cky_phase4<4, 2>(A, Bt, w, tid);
    for (int w = 64; w < SEQ; w += 4) cky_phase4<8, 3>(A, Bt, w, tid);

    if (tid == 0) {
        const int len = lenbuf[b];
        const float pred = A[len - 1];        // A[0][len-1]
        float margin = pred - gold[b];
        margin = margin > 0.0f ? margin : 0.0f;
        atomicAdd(out, margin * (1.0f / (float)BATCH));
    }
}

extern "C" void kernel_launch(void* const* d_in, const int* in_sizes, int n_in,
                              void* d_out, int out_size, void* d_ws, size_t ws_size,
                              hipStream_t stream) {
    const float* logits = (const float*)d_in[0];
    const int* labels = (const int*)d_in[1];
    float* out = (float*)d_out;

    float* pot = (float*)d_ws;                          // B*N*N floats = 4 MB
    float* gold = pot + (size_t)BATCH * SEQ * SEQ;      // B floats
    int* lenbuf = (int*)(gold + BATCH);                 // B ints

    (void)hipMemsetAsync(out, 0, sizeof(float), stream);

    len_kernel<<<BATCH, 64, 0, stream>>>(labels, lenbuf, gold);
    pot_gold_kernel<<<BATCH * SEQ * SEQ / 256, 256, 0, stream>>>(
        logits, labels, lenbuf, pot, gold);
    cky_kernel<<<BATCH, 512, 0, stream>>>(pot, gold, lenbuf, out);
}